// Round 2
// baseline (126.916 us; speedup 1.0000x reference)
//
#include <hip/hip_runtime.h>
#include <hip/hip_bf16.h>

#define NN 8192
#define KK 256
#define HN 4096
#define BM 256
#define BN 256
#define BK 64

typedef __attribute__((ext_vector_type(8))) short bf16x8;
typedef __attribute__((ext_vector_type(4))) float f32x4;

__device__ __forceinline__ void gload_lds16(const void* g, void* l) {
  __builtin_amdgcn_global_load_lds(
      (const __attribute__((address_space(1))) unsigned int*)g,
      (__attribute__((address_space(3))) unsigned int*)l, 16, 0, 0);
}

// ---- Kernel 1: row-normalize z (f32) -> zn (bf16); also zero rowsum ----
__global__ void nrm_kernel(const float* __restrict__ z,
                           unsigned short* __restrict__ zn,
                           float* __restrict__ rowsum) {
  if (blockIdx.x < 32) rowsum[(blockIdx.x << 8) + threadIdx.x] = 0.0f;
  int row = (blockIdx.x << 2) + (threadIdx.x >> 6);
  int lane = threadIdx.x & 63;
  float4 v = ((const float4*)(z + (size_t)row * KK))[lane];
  float ss = v.x * v.x + v.y * v.y + v.z * v.z + v.w * v.w;
#pragma unroll
  for (int off = 32; off; off >>= 1) ss += __shfl_xor(ss, off, 64);
  float scale = 1.0f / fmaxf(sqrtf(ss), 1e-8f);
  union {
    __hip_bfloat16 h[4];
    ushort4 u;
  } cv;
  cv.h[0] = __float2bfloat16(v.x * scale);
  cv.h[1] = __float2bfloat16(v.y * scale);
  cv.h[2] = __float2bfloat16(v.z * scale);
  cv.h[3] = __float2bfloat16(v.w * scale);
  ((ushort4*)zn)[(size_t)row * 64 + lane] = cv.u;
}

// ---- Kernel 2: fused Gram-GEMM + exp + row-sum + positive extraction ----
// 256x256 tile, 8 waves, double-buffered LDS, prefetch (T3 2-phase).
__global__ __launch_bounds__(512, 2) void gemm_kernel(
    const unsigned short* __restrict__ zn, float* __restrict__ rowsum,
    float* __restrict__ pos) {
  __shared__ short As[2][BM * BK];  // 2 x 32 KiB
  __shared__ short Bs[2][BN * BK];  // 2 x 32 KiB

  const int t = threadIdx.x;
  const int bm = blockIdx.x >> 5;
  const int bn = blockIdx.x & 31;
  const int l = t & 63;
  const int w = t >> 6;   // 0..7
  const int wr = w >> 2;  // 0..1 : 128 rows each
  const int wc = w & 3;   // 0..3 : 64 cols each

  f32x4 acc[8][4];
  const f32x4 vzero = {0.f, 0.f, 0.f, 0.f};
#pragma unroll
  for (int mi = 0; mi < 8; ++mi)
#pragma unroll
    for (int ni = 0; ni < 4; ++ni) acc[mi][ni] = vzero;

  const char* zb = (const char*)zn;
  const int rloc = t >> 3;                // 0..63 (row within 64-row round)
  const int gsrc = (t & 7) ^ (rloc & 7);  // pre-swizzled global 16B-group

  // stage one BK=64 K-slice of A (256 rows) and B (256 rows) into buf
#define STAGE(buf, kt)                                                        \
  do {                                                                        \
    _Pragma("unroll") for (int ro = 0; ro < 4; ++ro) {                        \
      int r = ro * 64 + rloc;                                                 \
      gload_lds16(zb + (size_t)(bm * BM + r) * 512 + (kt)*128 + gsrc * 16,    \
                  (char*)(&As[buf][0]) + ro * 8192 + t * 16);                 \
      gload_lds16(zb + (size_t)(bn * BN + r) * 512 + (kt)*128 + gsrc * 16,    \
                  (char*)(&Bs[buf][0]) + ro * 8192 + t * 16);                 \
    }                                                                         \
  } while (0)

  STAGE(0, 0);
  asm volatile("s_waitcnt vmcnt(0)" ::: "memory");
  __syncthreads();

#pragma unroll
  for (int kt = 0; kt < KK / BK; ++kt) {
    const int cur = kt & 1;
    if (kt < KK / BK - 1) STAGE(cur ^ 1, kt + 1);  // prefetch next slice
#pragma unroll
    for (int kk = 0; kk < 2; ++kk) {
      bf16x8 af[8], bfr[4];
      int g = kk * 4 + (l >> 4);
#pragma unroll
      for (int mi = 0; mi < 8; ++mi) {
        int r = wr * 128 + mi * 16 + (l & 15);
        af[mi] = *(const bf16x8*)(&As[cur][0] + r * 64 + ((g ^ (r & 7)) << 3));
      }
#pragma unroll
      for (int ni = 0; ni < 4; ++ni) {
        int r = wc * 64 + ni * 16 + (l & 15);
        bfr[ni] = *(const bf16x8*)(&Bs[cur][0] + r * 64 + ((g ^ (r & 7)) << 3));
      }
#pragma unroll
      for (int mi = 0; mi < 8; ++mi)
#pragma unroll
        for (int ni = 0; ni < 4; ++ni)
          acc[mi][ni] = __builtin_amdgcn_mfma_f32_16x16x32_bf16(
              af[mi], bfr[ni], acc[mi][ni], 0, 0, 0);
    }
    if (kt < KK / BK - 1) {
      asm volatile("s_waitcnt vmcnt(0)" ::: "memory");
      __syncthreads();
    }
  }

  // ---- epilogue: exp(10*s - 10), mask diagonal, grab positive, row-sum ----
  const int rowBase = bm * BM + wr * 128 + ((l >> 4) << 2);
  const int colBase = bn * BN + wc * 64 + (l & 15);
  const float C1 = 14.4269504088896340736f;  // 10*log2(e)
  float rs[8][4];
#pragma unroll
  for (int mi = 0; mi < 8; ++mi) {
#pragma unroll
    for (int j = 0; j < 4; ++j) rs[mi][j] = 0.f;
#pragma unroll
    for (int ni = 0; ni < 4; ++ni) {
#pragma unroll
      for (int j = 0; j < 4; ++j) {
        int gr = rowBase + mi * 16 + j;
        int gc = colBase + ni * 16;
        float a = acc[mi][ni][j];
        if (gc == (gr ^ HN)) pos[gr] = a * 10.0f;
        float p = (gc == gr) ? 0.0f : exp2f(fmaf(a, C1, -C1));
        rs[mi][j] += p;
      }
    }
  }
#pragma unroll
  for (int mi = 0; mi < 8; ++mi)
#pragma unroll
    for (int j = 0; j < 4; ++j) {
      float v = rs[mi][j];
#pragma unroll
      for (int off = 1; off < 16; off <<= 1) v += __shfl_xor(v, off, 64);
      if ((l & 15) == 0) atomicAdd(&rowsum[rowBase + mi * 16 + j], v);
    }
}

// ---- Kernel 3: loss = mean(10 + ln(rowsum_i) - pos_i) ----
__global__ void finalize_kernel(const float* __restrict__ rowsum,
                                const float* __restrict__ pos,
                                float* __restrict__ out) {
  int t = threadIdx.x;
  float acc = 0.f;
  for (int i = t; i < NN; i += 1024) acc += 10.0f + logf(rowsum[i]) - pos[i];
#pragma unroll
  for (int off = 32; off; off >>= 1) acc += __shfl_xor(acc, off, 64);
  __shared__ float ws[16];
  if ((t & 63) == 0) ws[t >> 6] = acc;
  __syncthreads();
  if (t == 0) {
    float s = 0.f;
#pragma unroll
    for (int i = 0; i < 16; ++i) s += ws[i];
    out[0] = s * (1.0f / (float)NN);
  }
}

extern "C" void kernel_launch(void* const* d_in, const int* in_sizes, int n_in,
                              void* d_out, int out_size, void* d_ws,
                              size_t ws_size, hipStream_t stream) {
  const float* z = (const float*)d_in[0];
  float* out = (float*)d_out;
  unsigned short* zn = (unsigned short*)d_ws;                   // 4 MiB bf16
  float* rowsum = (float*)((char*)d_ws + (size_t)NN * KK * 2);  // 32 KiB
  float* pos = rowsum + NN;                                     // 32 KiB

  nrm_kernel<<<NN / 4, 256, 0, stream>>>(z, zn, rowsum);
  gemm_kernel<<<(NN / BM) * (NN / BN), 512, 0, stream>>>(zn, rowsum, pos);
  finalize_kernel<<<1, 1024, 0, stream>>>(rowsum, pos, out);
}

// Round 3
// 72.470 us; speedup vs baseline: 1.7513x; 1.7513x over previous
//
#include <hip/hip_runtime.h>
#include <hip/hip_bf16.h>

#define NN 8192
#define KK 256
#define HN 4096
#define TM 256
#define TN 128
#define BK 64
#define NBLK 1056  // lower-triangle tiles: sum_{bm=0..31}(2bm+2) = 8*132

typedef __attribute__((ext_vector_type(8))) short bf16x8;
typedef __attribute__((ext_vector_type(4))) float f32x4;

__device__ __forceinline__ void gload_lds16(const void* g, void* l) {
  __builtin_amdgcn_global_load_lds(
      (const __attribute__((address_space(1))) unsigned int*)g,
      (__attribute__((address_space(3))) unsigned int*)l, 16, 0, 0);
}

// ---- Kernel 1: row-normalize z (f32) -> zn (bf16); also zero rowsum ----
__global__ void nrm_kernel(const float* __restrict__ z,
                           unsigned short* __restrict__ zn,
                           float* __restrict__ rowsum) {
  if (blockIdx.x < 32) rowsum[(blockIdx.x << 8) + threadIdx.x] = 0.0f;
  int row = (blockIdx.x << 2) + (threadIdx.x >> 6);
  int lane = threadIdx.x & 63;
  float4 v = ((const float4*)(z + (size_t)row * KK))[lane];
  float ss = v.x * v.x + v.y * v.y + v.z * v.z + v.w * v.w;
#pragma unroll
  for (int off = 32; off; off >>= 1) ss += __shfl_xor(ss, off, 64);
  float scale = 1.0f / fmaxf(sqrtf(ss), 1e-8f);
  union {
    __hip_bfloat16 h[4];
    ushort4 u;
  } cv;
  cv.h[0] = __float2bfloat16(v.x * scale);
  cv.h[1] = __float2bfloat16(v.y * scale);
  cv.h[2] = __float2bfloat16(v.z * scale);
  cv.h[3] = __float2bfloat16(v.w * scale);
  ((ushort4*)zn)[(size_t)row * 64 + lane] = cv.u;
}

// ---- Kernel 2: symmetric Gram-GEMM, lower-triangle tiles only ----
// Each exp(10*s_ij - 10) with j<i is credited to rowsum[i] (row reduce)
// and rowsum[j] (col reduce). pos pairs (i, i^4096) hit exactly one
// strictly-lower tile; write both directions there.
__global__ __launch_bounds__(256, 2) void gemm_kernel(
    const unsigned short* __restrict__ zn, float* __restrict__ rowsum,
    float* __restrict__ pos) {
  __shared__ short As[TM * BK];  // 32 KiB, XOR-swizzled 16B groups
  __shared__ short Bs[TN * BK];  // 16 KiB

  const int t = threadIdx.x;
  // XCD-aware swizzle (1056 = 8*132, bijective), then lower-tri decode
  int id = ((int)blockIdx.x & 7) * 132 + ((int)blockIdx.x >> 3);
  int bm = (int)((sqrtf((float)(4 * id + 1)) - 1.0f) * 0.5f);
  while (bm * (bm + 1) > id) --bm;
  while ((bm + 1) * (bm + 2) <= id) ++bm;
  const int bn = id - bm * (bm + 1);  // 0 .. 2*bm+1

  const int l = t & 63;
  const int w = t >> 6;   // 0..3
  const int wr = w >> 1;  // 0..1 : 128 rows
  const int wc = w & 1;   // 0..1 : 64 cols

  f32x4 acc[8][4];
  const f32x4 vzero = {0.f, 0.f, 0.f, 0.f};
#pragma unroll
  for (int mi = 0; mi < 8; ++mi)
#pragma unroll
    for (int ni = 0; ni < 4; ++ni) acc[mi][ni] = vzero;

  const char* zb = (const char*)zn;
  const int rloc = t >> 3;                // 0..31
  const int gsrc = (t & 7) ^ (rloc & 7);  // pre-swizzled source 16B-group

#pragma unroll
  for (int kt = 0; kt < KK / BK; ++kt) {
    if (kt) __syncthreads();  // previous tile fully consumed
#pragma unroll
    for (int ro = 0; ro < 8; ++ro) {  // A: 256 rows
      int r = ro * 32 + rloc;
      gload_lds16(zb + (size_t)(bm * TM + r) * 512 + kt * 128 + gsrc * 16,
                  (char*)As + ro * 4096 + t * 16);
    }
#pragma unroll
    for (int ro = 0; ro < 4; ++ro) {  // B: 128 rows
      int r = ro * 32 + rloc;
      gload_lds16(zb + (size_t)(bn * TN + r) * 512 + kt * 128 + gsrc * 16,
                  (char*)Bs + ro * 4096 + t * 16);
    }
    asm volatile("s_waitcnt vmcnt(0)" ::: "memory");
    __syncthreads();

#pragma unroll
    for (int kk = 0; kk < 2; ++kk) {
      bf16x8 af[8], bfr[4];
      int g = kk * 4 + (l >> 4);
#pragma unroll
      for (int mi = 0; mi < 8; ++mi) {
        int r = wr * 128 + mi * 16 + (l & 15);
        af[mi] = *(const bf16x8*)(As + r * 64 + ((g ^ (r & 7)) << 3));
      }
#pragma unroll
      for (int ni = 0; ni < 4; ++ni) {
        int r = wc * 64 + ni * 16 + (l & 15);
        bfr[ni] = *(const bf16x8*)(Bs + r * 64 + ((g ^ (r & 7)) << 3));
      }
#pragma unroll
      for (int mi = 0; mi < 8; ++mi)
#pragma unroll
        for (int ni = 0; ni < 4; ++ni)
          acc[mi][ni] = __builtin_amdgcn_mfma_f32_16x16x32_bf16(
              af[mi], bfr[ni], acc[mi][ni], 0, 0, 0);
    }
  }

  // ---- epilogue: p = exp(10s-10) for gc<gr only; row + col sums ----
  const int rowBase = bm * TM + wr * 128 + ((l >> 4) << 2);
  const int colBase = bn * TN + wc * 64 + (l & 15);
  const float C1 = 14.4269504088896340736f;  // 10*log2(e)
  float rs[8][4];
  float cs[4] = {0.f, 0.f, 0.f, 0.f};
#pragma unroll
  for (int mi = 0; mi < 8; ++mi) {
#pragma unroll
    for (int j = 0; j < 4; ++j) rs[mi][j] = 0.f;
#pragma unroll
    for (int ni = 0; ni < 4; ++ni) {
#pragma unroll
      for (int j = 0; j < 4; ++j) {
        int gr = rowBase + mi * 16 + j;
        int gc = colBase + ni * 16;
        float a = acc[mi][ni][j];
        if (gc == (gr ^ HN)) {  // strictly-lower hit: write both directions
          pos[gr] = a * 10.0f;
          pos[gc] = a * 10.0f;
        }
        float p = (gc < gr) ? exp2f(fmaf(a, C1, -C1)) : 0.0f;
        rs[mi][j] += p;
        cs[ni] += p;
      }
    }
  }
#pragma unroll
  for (int mi = 0; mi < 8; ++mi)
#pragma unroll
    for (int j = 0; j < 4; ++j) {
      float v = rs[mi][j];
      v += __shfl_xor(v, 1, 64);
      v += __shfl_xor(v, 2, 64);
      v += __shfl_xor(v, 4, 64);
      v += __shfl_xor(v, 8, 64);
      if ((l & 15) == 0) atomicAdd(&rowsum[rowBase + mi * 16 + j], v);
    }
#pragma unroll
  for (int ni = 0; ni < 4; ++ni) {
    float v = cs[ni];
    v += __shfl_xor(v, 16, 64);
    v += __shfl_xor(v, 32, 64);
    if (l < 16) atomicAdd(&rowsum[colBase + ni * 16], v);
  }
}

// ---- Kernel 3: loss = mean(10 + ln(rowsum_i) - pos_i) ----
__global__ void finalize_kernel(const float* __restrict__ rowsum,
                                const float* __restrict__ pos,
                                float* __restrict__ out) {
  int t = threadIdx.x;
  float acc = 0.f;
  for (int i = t; i < NN; i += 1024) acc += 10.0f + logf(rowsum[i]) - pos[i];
#pragma unroll
  for (int off = 32; off; off >>= 1) acc += __shfl_xor(acc, off, 64);
  __shared__ float ws[16];
  if ((t & 63) == 0) ws[t >> 6] = acc;
  __syncthreads();
  if (t == 0) {
    float s = 0.f;
#pragma unroll
    for (int i = 0; i < 16; ++i) s += ws[i];
    out[0] = s * (1.0f / (float)NN);
  }
}

extern "C" void kernel_launch(void* const* d_in, const int* in_sizes, int n_in,
                              void* d_out, int out_size, void* d_ws,
                              size_t ws_size, hipStream_t stream) {
  const float* z = (const float*)d_in[0];
  float* out = (float*)d_out;
  unsigned short* zn = (unsigned short*)d_ws;                   // 4 MiB bf16
  float* rowsum = (float*)((char*)d_ws + (size_t)NN * KK * 2);  // 32 KiB
  float* pos = rowsum + NN;                                     // 32 KiB

  nrm_kernel<<<NN / 4, 256, 0, stream>>>(z, zn, rowsum);
  gemm_kernel<<<NBLK, 256, 0, stream>>>(zn, rowsum, pos);
  finalize_kernel<<<1, 1024, 0, stream>>>(rowsum, pos, out);
}

// Round 4
// 57.645 us; speedup vs baseline: 2.2017x; 1.2572x over previous
//
#include <hip/hip_runtime.h>
#include <hip/hip_bf16.h>

#define NN 8192
#define KK 256
#define HN 4096
#define TM 256
#define TN 128
#define BK 64
#define NBLK 1056  // lower-triangle tiles: sum_{bm=0..31}(2bm+2) = 8*132

typedef __attribute__((ext_vector_type(8))) short bf16x8;
typedef __attribute__((ext_vector_type(4))) float f32x4;

__device__ __forceinline__ void gload_lds16(const void* g, void* l) {
  __builtin_amdgcn_global_load_lds(
      (const __attribute__((address_space(1))) unsigned int*)g,
      (__attribute__((address_space(3))) unsigned int*)l, 16, 0, 0);
}

// ---- Kernel 1: row-normalize z (f32) -> zn (bf16) ----
__global__ void nrm_kernel(const float* __restrict__ z,
                           unsigned short* __restrict__ zn) {
  int row = (blockIdx.x << 2) + (threadIdx.x >> 6);
  int lane = threadIdx.x & 63;
  float4 v = ((const float4*)(z + (size_t)row * KK))[lane];
  float ss = v.x * v.x + v.y * v.y + v.z * v.z + v.w * v.w;
#pragma unroll
  for (int off = 32; off; off >>= 1) ss += __shfl_xor(ss, off, 64);
  float scale = 1.0f / fmaxf(sqrtf(ss), 1e-8f);
  union {
    __hip_bfloat16 h[4];
    ushort4 u;
  } cv;
  cv.h[0] = __float2bfloat16(v.x * scale);
  cv.h[1] = __float2bfloat16(v.y * scale);
  cv.h[2] = __float2bfloat16(v.z * scale);
  cv.h[3] = __float2bfloat16(v.w * scale);
  ((ushort4*)zn)[(size_t)row * 64 + lane] = cv.u;
}

// ---- Kernel 2: symmetric Gram-GEMM, lower-triangle tiles only ----
// p = exp(10*s_ij - 10) for j<i credited to row i and col j partial sums.
// NO global atomics: block (bm,bn) writes rowpartT[row][bn] (after LDS merge
// of the two wc waves) and colpartT[col][bm] (after merge of the two wr
// waves). pos pairs (i, i^4096) hit exactly one strictly-lower tile.
__global__ __launch_bounds__(256, 2) void gemm_kernel(
    const unsigned short* __restrict__ zn, float* __restrict__ rowpartT,
    float* __restrict__ colpartT, float* __restrict__ pos) {
  __shared__ short As[TM * BK];  // 32 KiB, XOR-swizzled 16B groups
  __shared__ short Bs[TN * BK];  // 16 KiB

  const int t = threadIdx.x;
  // XCD-aware swizzle (1056 = 8*132, bijective), then lower-tri decode
  int id = ((int)blockIdx.x & 7) * 132 + ((int)blockIdx.x >> 3);
  int bm = (int)((sqrtf((float)(4 * id + 1)) - 1.0f) * 0.5f);
  while (bm * (bm + 1) > id) --bm;
  while ((bm + 1) * (bm + 2) <= id) ++bm;
  const int bn = id - bm * (bm + 1);  // 0 .. 2*bm+1

  const int l = t & 63;
  const int w = t >> 6;   // 0..3
  const int wr = w >> 1;  // 0..1 : 128 rows
  const int wc = w & 1;   // 0..1 : 64 cols

  f32x4 acc[8][4];
  const f32x4 vzero = {0.f, 0.f, 0.f, 0.f};
#pragma unroll
  for (int mi = 0; mi < 8; ++mi)
#pragma unroll
    for (int ni = 0; ni < 4; ++ni) acc[mi][ni] = vzero;

  const char* zb = (const char*)zn;
  const int rloc = t >> 3;                // 0..31
  const int gsrc = (t & 7) ^ (rloc & 7);  // pre-swizzled source 16B-group

#pragma unroll
  for (int kt = 0; kt < KK / BK; ++kt) {
    if (kt) __syncthreads();  // previous tile fully consumed
#pragma unroll
    for (int ro = 0; ro < 8; ++ro) {  // A: 256 rows
      int r = ro * 32 + rloc;
      gload_lds16(zb + (size_t)(bm * TM + r) * 512 + kt * 128 + gsrc * 16,
                  (char*)As + ro * 4096 + t * 16);
    }
#pragma unroll
    for (int ro = 0; ro < 4; ++ro) {  // B: 128 rows
      int r = ro * 32 + rloc;
      gload_lds16(zb + (size_t)(bn * TN + r) * 512 + kt * 128 + gsrc * 16,
                  (char*)Bs + ro * 4096 + t * 16);
    }
    asm volatile("s_waitcnt vmcnt(0)" ::: "memory");
    __syncthreads();

#pragma unroll
    for (int kk = 0; kk < 2; ++kk) {
      bf16x8 af[8], bfr[4];
      int g = kk * 4 + (l >> 4);
#pragma unroll
      for (int mi = 0; mi < 8; ++mi) {
        int r = wr * 128 + mi * 16 + (l & 15);
        af[mi] = *(const bf16x8*)(As + r * 64 + ((g ^ (r & 7)) << 3));
      }
#pragma unroll
      for (int ni = 0; ni < 4; ++ni) {
        int r = wc * 64 + ni * 16 + (l & 15);
        bfr[ni] = *(const bf16x8*)(Bs + r * 64 + ((g ^ (r & 7)) << 3));
      }
#pragma unroll
      for (int mi = 0; mi < 8; ++mi)
#pragma unroll
        for (int ni = 0; ni < 4; ++ni)
          acc[mi][ni] = __builtin_amdgcn_mfma_f32_16x16x32_bf16(
              af[mi], bfr[ni], acc[mi][ni], 0, 0, 0);
    }
  }

  // ---- epilogue: p = exp(10s-10) for gc<gr only; row + col partials ----
  const int g16 = l >> 4;  // accumulator row group
  const int rowBase = bm * TM + wr * 128 + (g16 << 2);
  const int colBase = bn * TN + wc * 64 + (l & 15);
  const float C1 = 14.4269504088896340736f;  // 10*log2(e)
  float rs[8][4];
  float cs[4] = {0.f, 0.f, 0.f, 0.f};
#pragma unroll
  for (int mi = 0; mi < 8; ++mi) {
#pragma unroll
    for (int j = 0; j < 4; ++j) rs[mi][j] = 0.f;
#pragma unroll
    for (int ni = 0; ni < 4; ++ni) {
#pragma unroll
      for (int j = 0; j < 4; ++j) {
        int gr = rowBase + mi * 16 + j;
        int gc = colBase + ni * 16;
        float a = acc[mi][ni][j];
        if (gc == (gr ^ HN)) {  // strictly-lower hit: write both directions
          pos[gr] = a * 10.0f;
          pos[gc] = a * 10.0f;
        }
        float p = (gc < gr) ? exp2f(fmaf(a, C1, -C1)) : 0.0f;
        rs[mi][j] += p;
        cs[ni] += p;
      }
    }
  }
  // reduce rs across the 16 col-lanes; cs across the 4 row-lane-groups
#pragma unroll
  for (int mi = 0; mi < 8; ++mi)
#pragma unroll
    for (int j = 0; j < 4; ++j) {
      float v = rs[mi][j];
      v += __shfl_xor(v, 1, 64);
      v += __shfl_xor(v, 2, 64);
      v += __shfl_xor(v, 4, 64);
      v += __shfl_xor(v, 8, 64);
      rs[mi][j] = v;  // valid in lanes with (l&15)==0
    }
#pragma unroll
  for (int ni = 0; ni < 4; ++ni) {
    float v = cs[ni];
    v += __shfl_xor(v, 16, 64);
    v += __shfl_xor(v, 32, 64);
    cs[ni] = v;  // valid in lanes l<16
  }

  // merge wave pairs via LDS (reuse As), then ONE writer per slot
  float* red = (float*)As;  // [0..255]: rows, [256..383]: cols
  __syncthreads();          // all MFMA LDS reads done
  if (wc == 1 && (l & 15) == 0) {
#pragma unroll
    for (int mi = 0; mi < 8; ++mi)
#pragma unroll
      for (int j = 0; j < 4; ++j)
        red[wr * 128 + mi * 16 + (g16 << 2) + j] = rs[mi][j];
  }
  if (wr == 1 && l < 16) {
#pragma unroll
    for (int ni = 0; ni < 4; ++ni) red[256 + wc * 64 + ni * 16 + l] = cs[ni];
  }
  __syncthreads();
  if (wc == 0 && (l & 15) == 0) {
#pragma unroll
    for (int mi = 0; mi < 8; ++mi)
#pragma unroll
      for (int j = 0; j < 4; ++j) {
        int off = mi * 16 + (g16 << 2) + j;
        rowpartT[(size_t)(bm * TM + wr * 128 + off) * 64 + bn] =
            rs[mi][j] + red[wr * 128 + off];
      }
  }
  if (wr == 0 && l < 16) {
#pragma unroll
    for (int ni = 0; ni < 4; ++ni) {
      int c = bn * TN + wc * 64 + ni * 16 + l;
      colpartT[(size_t)c * 32 + bm] = cs[ni] + red[256 + wc * 64 + ni * 16 + l];
    }
  }
}

// ---- Kernel 3: loss = mean(10 + ln(rowsum_i) - pos_i), rowsum from partials
__global__ void finalize_kernel(const float* __restrict__ rowpartT,
                                const float* __restrict__ colpartT,
                                const float* __restrict__ pos,
                                float* __restrict__ out) {
  int i = blockIdx.x * 256 + threadIdx.x;  // one row per thread
  int bm = i >> 8, cn = i >> 7;
  float s = 0.f;
  const float* rp = rowpartT + (size_t)i * 64;
  int nr = 2 * bm + 2;  // always even
  for (int k = 0; k < nr; k += 2) {
    float2 v = *(const float2*)(rp + k);
    s += v.x + v.y;
  }
  const float* cp = colpartT + (size_t)i * 32;
  for (int k = (cn >> 1); k < 32; ++k) s += cp[k];
  float acc = 10.0f + logf(s) - pos[i];
#pragma unroll
  for (int off = 32; off; off >>= 1) acc += __shfl_xor(acc, off, 64);
  __shared__ float ws[4];
  if ((threadIdx.x & 63) == 0) ws[threadIdx.x >> 6] = acc;
  __syncthreads();
  if (threadIdx.x == 0)
    atomicAdd(out, (ws[0] + ws[1] + ws[2] + ws[3]) * (1.0f / (float)NN));
}

extern "C" void kernel_launch(void* const* d_in, const int* in_sizes, int n_in,
                              void* d_out, int out_size, void* d_ws,
                              size_t ws_size, hipStream_t stream) {
  const float* z = (const float*)d_in[0];
  float* out = (float*)d_out;
  char* ws = (char*)d_ws;
  unsigned short* zn = (unsigned short*)ws;              // 4 MiB bf16
  float* rowpartT = (float*)(ws + (4 << 20));            // 2 MiB [8192][64]
  float* colpartT = (float*)(ws + (6 << 20));            // 1 MiB [8192][32]
  float* pos = (float*)(ws + (7 << 20));                 // 32 KiB

  nrm_kernel<<<NN / 4, 256, 0, stream>>>(z, zn);
  gemm_kernel<<<NBLK, 256, 0, stream>>>(zn, rowpartT, colpartT, pos);
  hipMemsetAsync(out, 0, sizeof(float), stream);
  finalize_kernel<<<NN / 256, 256, 0, stream>>>(rowpartT, colpartT, pos, out);
}